// Round 2
// baseline (2921.065 us; speedup 1.0000x reference)
//
#include <hip/hip_runtime.h>

// MessagePassingLayer, Round 2: CSR-gather instead of atomic scatter.
// Round-1 post-mortem: 11.26 GB of HBM write traffic from 1.02e8 scattered 4B
// global atomics (write amplification at the coherent point) = 2.4 ms of the
// 2.75 ms. Fix: build CSR (by target) on device, compute messages in CSR
// position order (coalesced float4 stores, no atomics), then per-node
// contiguous gather. Round-1 atomic path kept as ws_size fallback.

#define HID 64
#define SCAN_CHUNK 1024

// ---------------- MLP core (shared) ----------------
__device__ __forceinline__ void fma_row4(float* __restrict__ hid, const float4 x,
                                         const float* __restrict__ w) {
#pragma unroll
  for (int j = 0; j < HID; ++j) {
    float t = fmaf(x.x, w[j], hid[j]);
    t = fmaf(x.y, w[64 + j], t);
    t = fmaf(x.z, w[128 + j], t);
    t = fmaf(x.w, w[192 + j], t);
    hid[j] = t;
  }
}

__device__ __forceinline__ void edge_mlp_core(const float* __restrict__ h, int src, int tgt,
                                              const float* __restrict__ ef, int e,
                                              const float* __restrict__ W1, const float* __restrict__ b1,
                                              const float* __restrict__ W2, const float* __restrict__ b2,
                                              float* __restrict__ msg) {
  float hid[HID];
#pragma unroll
  for (int j = 0; j < HID; ++j) hid[j] = b1[j];
  const float4* __restrict__ xs = (const float4*)(h + (size_t)src * 64);
#pragma unroll 2
  for (int kk = 0; kk < 16; ++kk) fma_row4(hid, xs[kk], W1 + (size_t)(kk * 4) * 64);
  const float4* __restrict__ xt = (const float4*)(h + (size_t)tgt * 64);
#pragma unroll 2
  for (int kk = 0; kk < 16; ++kk) fma_row4(hid, xt[kk], W1 + (size_t)(64 + kk * 4) * 64);
  const float4* __restrict__ xe = (const float4*)(ef + (size_t)e * 32);
#pragma unroll 2
  for (int kk = 0; kk < 8; ++kk) fma_row4(hid, xe[kk], W1 + (size_t)(128 + kk * 4) * 64);
#pragma unroll
  for (int j = 0; j < HID; ++j) msg[j] = b2[j];
#pragma unroll 2
  for (int k = 0; k < HID; ++k) {
    const float av = fmaxf(hid[k], 0.0f);
    const float* __restrict__ w = W2 + (size_t)k * 64;
#pragma unroll
    for (int j = 0; j < HID; ++j) msg[j] = fmaf(av, w[j], msg[j]);
  }
}

// ---------------- CSR build ----------------
__global__ void hist_deg(const int* __restrict__ ei, int* __restrict__ deg, int E) {
  for (long long e = (long long)blockIdx.x * blockDim.x + threadIdx.x; e < E;
       e += (long long)gridDim.x * blockDim.x) {
    atomicAdd(&deg[ei[E + e]], 1);
  }
}

__global__ void scan_chunks(const int* __restrict__ deg, int* __restrict__ start,
                            int* __restrict__ chunk_sums, int N) {
  __shared__ int sdata[256];
  const int tid = threadIdx.x;
  const int base = blockIdx.x * SCAN_CHUNK + tid * 4;
  int v[4];
  int sum = 0;
#pragma unroll
  for (int k = 0; k < 4; ++k) {
    v[k] = (base + k < N) ? deg[base + k] : 0;
    sum += v[k];
  }
  sdata[tid] = sum;
  __syncthreads();
  // Hillis-Steele inclusive scan over 256 thread sums
  for (int off = 1; off < 256; off <<= 1) {
    int t = (tid >= off) ? sdata[tid - off] : 0;
    __syncthreads();
    sdata[tid] += t;
    __syncthreads();
  }
  int run = (tid == 0) ? 0 : sdata[tid - 1];  // exclusive prefix of this thread's group
#pragma unroll
  for (int k = 0; k < 4; ++k) {
    if (base + k < N) start[base + k] = run;
    run += v[k];
  }
  if (tid == 255) chunk_sums[blockIdx.x] = sdata[255];
}

__global__ void scan_sums(const int* __restrict__ chunk_sums, int* __restrict__ chunk_offs,
                          int nchunks) {
  __shared__ int s[1024];
  const int tid = threadIdx.x;
  for (int i = tid; i < nchunks; i += blockDim.x) s[i] = chunk_sums[i];
  __syncthreads();
  if (tid == 0) {
    int run = 0;
    for (int i = 0; i < nchunks; ++i) { int v = s[i]; s[i] = run; run += v; }
  }
  __syncthreads();
  for (int i = tid; i < nchunks; i += blockDim.x) chunk_offs[i] = s[i];
}

__global__ void add_offsets(int* __restrict__ start, const int* __restrict__ chunk_offs,
                            int* __restrict__ cursor, int N) {
  const int i = blockIdx.x * blockDim.x + threadIdx.x;
  if (i < N) {
    const int sgl = start[i] + chunk_offs[i / SCAN_CHUNK];
    start[i] = sgl;
    cursor[i] = sgl;
  }
}

__global__ void fill_elist(const int* __restrict__ ei, int* __restrict__ cursor,
                           int* __restrict__ elist, int E) {
  for (long long e = (long long)blockIdx.x * blockDim.x + threadIdx.x; e < E;
       e += (long long)gridDim.x * blockDim.x) {
    const int t = ei[E + e];
    const int pos = atomicAdd(&cursor[t], 1);
    elist[pos] = (int)e;
  }
}

// ---------------- main kernels ----------------
__global__ __launch_bounds__(256, 2)
void edge_mlp_csr(const float* __restrict__ h, const int* __restrict__ ei,
                  const float* __restrict__ ef,
                  const float* __restrict__ W1, const float* __restrict__ b1,
                  const float* __restrict__ W2, const float* __restrict__ b2,
                  const int* __restrict__ elist, float* __restrict__ msgbuf, int E) {
  const long long p = (long long)blockIdx.x * 256 + threadIdx.x;
  if (p >= E) return;
  const int e = elist[p];
  const int src = ei[e];
  const int tgt = ei[E + e];

  float msg[HID];
  edge_mlp_core(h, src, tgt, ef, e, W1, b1, W2, b2, msg);

  float4* __restrict__ po = (float4*)(msgbuf + (size_t)p * 64);
#pragma unroll
  for (int j4 = 0; j4 < 16; ++j4)
    po[j4] = make_float4(msg[4 * j4], msg[4 * j4 + 1], msg[4 * j4 + 2], msg[4 * j4 + 3]);
}

__global__ __launch_bounds__(256)
void gather_agg(const float* __restrict__ msgbuf, const int* __restrict__ start,
                const int* __restrict__ deg, float* __restrict__ agg, int N) {
  const int n = blockIdx.x * 4 + (threadIdx.x >> 6);
  const int lane = threadIdx.x & 63;
  if (n >= N) return;
  const int s = start[n];
  const int d = deg[n];
  const float* __restrict__ base = msgbuf + (size_t)s * 64 + lane;
  float a0 = 0.f, a1 = 0.f, a2 = 0.f, a3 = 0.f;
  int i = 0;
  for (; i + 4 <= d; i += 4) {
    a0 += base[(size_t)(i + 0) * 64];
    a1 += base[(size_t)(i + 1) * 64];
    a2 += base[(size_t)(i + 2) * 64];
    a3 += base[(size_t)(i + 3) * 64];
  }
  for (; i < d; ++i) a0 += base[(size_t)i * 64];
  agg[(size_t)n * 64 + lane] = (a0 + a1) + (a2 + a3);
}

__global__ __launch_bounds__(256, 2)
void node_update(const float* __restrict__ h, const float* __restrict__ agg,
                 const float* __restrict__ W1, const float* __restrict__ b1,
                 const float* __restrict__ W2, const float* __restrict__ b2,
                 float* __restrict__ out, int N) {
  const long long ng = (long long)blockIdx.x * blockDim.x + threadIdx.x;
  const bool valid = ng < N;
  const int n = valid ? (int)ng : 0;

  float hid[HID];
#pragma unroll
  for (int j = 0; j < HID; ++j) hid[j] = b1[j];
  const float4* __restrict__ xh = (const float4*)(h + (size_t)n * 64);
#pragma unroll 2
  for (int kk = 0; kk < 16; ++kk) fma_row4(hid, xh[kk], W1 + (size_t)(kk * 4) * 64);
  const float4* __restrict__ xa = (const float4*)(agg + (size_t)n * 64);
#pragma unroll 2
  for (int kk = 0; kk < 16; ++kk) fma_row4(hid, xa[kk], W1 + (size_t)(64 + kk * 4) * 64);

  float o[HID];
#pragma unroll
  for (int j = 0; j < HID; ++j) o[j] = b2[j];
#pragma unroll 2
  for (int k = 0; k < HID; ++k) {
    const float av = fmaxf(hid[k], 0.0f);
    const float* __restrict__ w = W2 + (size_t)k * 64;
#pragma unroll
    for (int j = 0; j < HID; ++j) o[j] = fmaf(av, w[j], o[j]);
  }

  if (valid) {
    float4* __restrict__ po = (float4*)(out + (size_t)n * 64);
#pragma unroll
    for (int j4 = 0; j4 < 16; ++j4)
      po[j4] = make_float4(o[4 * j4], o[4 * j4 + 1], o[4 * j4 + 2], o[4 * j4 + 3]);
  }
}

// ---------------- round-1 fallback (atomic scatter) ----------------
__global__ __launch_bounds__(256, 2)
void edge_mlp_scatter(const float* __restrict__ h, const int* __restrict__ ei,
                      const float* __restrict__ ef,
                      const float* __restrict__ W1, const float* __restrict__ b1,
                      const float* __restrict__ W2, const float* __restrict__ b2,
                      float* __restrict__ agg, int E) {
  __shared__ float stage[4][64][68];
  const int tid = threadIdx.x;
  const int wave = tid >> 6;
  const int lane = tid & 63;
  const long long eg = (long long)blockIdx.x * 256 + tid;
  const int e = (eg < E) ? (int)eg : 0;
  const int src = ei[e];
  const int tgt = ei[E + e];
  float msg[HID];
  edge_mlp_core(h, src, tgt, ef, e, W1, b1, W2, b2, msg);
#pragma unroll
  for (int j4 = 0; j4 < 16; ++j4)
    *(float4*)&stage[wave][lane][4 * j4] =
        make_float4(msg[4 * j4], msg[4 * j4 + 1], msg[4 * j4 + 2], msg[4 * j4 + 3]);
  __syncthreads();
  const long long wave_base = (long long)blockIdx.x * 256 + wave * 64;
#pragma unroll 1
  for (int i = 0; i < 64; ++i) {
    if (wave_base + i < E) {
      const int t = __shfl(tgt, i);
      atomicAdd(agg + (size_t)t * 64 + lane, stage[wave][i][lane]);
    }
  }
}

// ---------------- host ----------------
extern "C" void kernel_launch(void* const* d_in, const int* in_sizes, int n_in,
                              void* d_out, int out_size, void* d_ws, size_t ws_size,
                              hipStream_t stream) {
  const float* h   = (const float*)d_in[0];
  const int*   ei  = (const int*)d_in[1];
  const float* ef  = (const float*)d_in[2];
  const float* eW1 = (const float*)d_in[3];
  const float* eb1 = (const float*)d_in[4];
  const float* eW2 = (const float*)d_in[5];
  const float* eb2 = (const float*)d_in[6];
  const float* uW1 = (const float*)d_in[7];
  const float* ub1 = (const float*)d_in[8];
  const float* uW2 = (const float*)d_in[9];
  const float* ub2 = (const float*)d_in[10];
  float* out = (float*)d_out;

  const int N = in_sizes[0] / 64;   // 100000
  const int E = in_sizes[1] / 2;    // 1600000
  const int nchunks = (N + SCAN_CHUNK - 1) / SCAN_CHUNK;

  // ws layout
  size_t off = 0;
  auto alloc = [&](size_t bytes) { size_t o = off; off += (bytes + 255) & ~(size_t)255; return o; };
  const size_t msg_off    = alloc((size_t)E * 64 * sizeof(float));   // 409.6 MB
  const size_t agg_off    = alloc((size_t)N * 64 * sizeof(float));   // 25.6 MB
  const size_t elist_off  = alloc((size_t)E * sizeof(int));          // 6.4 MB
  const size_t deg_off    = alloc((size_t)N * sizeof(int));
  const size_t start_off  = alloc((size_t)N * sizeof(int));
  const size_t cursor_off = alloc((size_t)N * sizeof(int));
  const size_t csum_off   = alloc((size_t)nchunks * sizeof(int));
  const size_t coff_off   = alloc((size_t)nchunks * sizeof(int));
  char* ws = (char*)d_ws;

  if (ws_size >= off) {
    float* msg   = (float*)(ws + msg_off);
    float* agg   = (float*)(ws + agg_off);
    int* elist   = (int*)(ws + elist_off);
    int* deg     = (int*)(ws + deg_off);
    int* start   = (int*)(ws + start_off);
    int* cursor  = (int*)(ws + cursor_off);
    int* csum    = (int*)(ws + csum_off);
    int* coff    = (int*)(ws + coff_off);

    hipMemsetAsync(deg, 0, (size_t)N * sizeof(int), stream);
    hist_deg<<<1024, 256, 0, stream>>>(ei, deg, E);
    scan_chunks<<<nchunks, 256, 0, stream>>>(deg, start, csum, N);
    scan_sums<<<1, 256, 0, stream>>>(csum, coff, nchunks);
    add_offsets<<<(N + 255) / 256, 256, 0, stream>>>(start, coff, cursor, N);
    fill_elist<<<1024, 256, 0, stream>>>(ei, cursor, elist, E);
    edge_mlp_csr<<<(E + 255) / 256, 256, 0, stream>>>(h, ei, ef, eW1, eb1, eW2, eb2, elist, msg, E);
    gather_agg<<<(N + 3) / 4, 256, 0, stream>>>(msg, start, deg, agg, N);
    node_update<<<(N + 255) / 256, 256, 0, stream>>>(h, agg, uW1, ub1, uW2, ub2, out, N);
  } else {
    // fallback: round-1 atomic-scatter path (needs only agg)
    float* agg = (float*)d_ws;
    hipMemsetAsync(agg, 0, (size_t)N * 64 * sizeof(float), stream);
    edge_mlp_scatter<<<(E + 255) / 256, 256, 0, stream>>>(h, ei, ef, eW1, eb1, eW2, eb2, agg, E);
    node_update<<<(N + 255) / 256, 256, 0, stream>>>(h, agg, uW1, ub1, uW2, ub2, out, N);
  }
}